// Round 5
// baseline (596.896 us; speedup 1.0000x reference)
//
#include <hip/hip_runtime.h>
#include <hip/hip_bf16.h>

typedef _Float16 f16x8 __attribute__((ext_vector_type(8)));
typedef _Float16 f16x4 __attribute__((ext_vector_type(4)));
typedef float f32x4 __attribute__((ext_vector_type(4)));

typedef __attribute__((address_space(1))) void GV;
typedef __attribute__((address_space(3))) void LV;

__device__ inline void async16(void* lds, const void* g) {
    __builtin_amdgcn_global_load_lds((GV*)g, (LV*)lds, 16, 0, 0);
}

// ---------------- cast f32 -> f16 ----------------
__global__ __launch_bounds__(256) void cast_kernel(const float* __restrict__ in,
                                                   _Float16* __restrict__ out, long n4) {
    long i = (long)blockIdx.x * blockDim.x + threadIdx.x;
    if (i < n4) {
        float4 v = ((const float4*)in)[i];
        f16x4 o;
        o[0] = (_Float16)v.x; o[1] = (_Float16)v.y;
        o[2] = (_Float16)v.z; o[3] = (_Float16)v.w;
        ((f16x4*)out)[i] = o;
    }
}

// ---------------- V transpose: in [b][s][e] -> out [b][e][s] ----------------
__global__ __launch_bounds__(256) void transpose_v(const _Float16* __restrict__ in,
                                                   _Float16* __restrict__ out) {
    __shared__ _Float16 tile[64][66];
    int b = blockIdx.z;
    long base = (long)b * 1048576;
    int s0 = blockIdx.x * 64, e0 = blockIdx.y * 64;
    int tc = threadIdx.x & 63, tr = threadIdx.x >> 6;  // tr in 0..3
    #pragma unroll
    for (int rr = 0; rr < 64; rr += 4)
        tile[tr + rr][tc] = in[base + (long)(s0 + tr + rr) * 1024 + e0 + tc];
    __syncthreads();
    #pragma unroll
    for (int rr = 0; rr < 64; rr += 4)
        out[base + (long)(e0 + tr + rr) * 1024 + s0 + tc] = tile[tc][tr + rr];
}

// ---------------- batched GEMM: C = A @ B^T, f32 accum ----------------
__global__ __launch_bounds__(256) void gemm_bt(
    const _Float16* __restrict__ A0, const _Float16* __restrict__ B0, void* __restrict__ C0,
    int K, int lda, int ldb, int ldc,
    int az_div, long sa_hi, long sa_lo, long sb,
    int cz_div, long sc_hi, long sc_lo, int out_f32)
{
    __shared__ _Float16 As[128 * 64];
    __shared__ _Float16 Bs[128 * 64];
    int z = blockIdx.z;
    const _Float16* A = A0 + (long)(z / az_div) * sa_hi + (long)(z % az_div) * sa_lo;
    const _Float16* B = B0 + (long)z * sb;
    long coff = (long)(z / cz_div) * sc_hi + (long)(z % cz_div) * sc_lo;
    int rowbase = blockIdx.y * 128, colbase = blockIdx.x * 128;
    int t = threadIdx.x, wave = t >> 6, lane = t & 63;
    int l15 = lane & 15, lg = lane >> 4;
    int srow = t >> 3, scol = (t & 7) * 8;
    int wm = wave >> 1, wn = wave & 1;
    f32x4 acc[4][4] = {};
    for (int k0 = 0; k0 < K; k0 += 64) {
        #pragma unroll
        for (int ii = 0; ii < 4; ii++) {
            int r = srow + ii * 32;
            async16(&As[r * 64 + scol], A + (long)(rowbase + r) * lda + k0 + scol);
            async16(&Bs[r * 64 + scol], B + (long)(colbase + r) * ldb + k0 + scol);
        }
        __syncthreads();
        #pragma unroll
        for (int ks = 0; ks < 2; ks++) {
            f16x8 af[4], bfr[4];
            #pragma unroll
            for (int m = 0; m < 4; m++)
                af[m] = *(const f16x8*)&As[(wm * 64 + m * 16 + l15) * 64 + ks * 32 + lg * 8];
            #pragma unroll
            for (int n = 0; n < 4; n++)
                bfr[n] = *(const f16x8*)&Bs[(wn * 64 + n * 16 + l15) * 64 + ks * 32 + lg * 8];
            #pragma unroll
            for (int m = 0; m < 4; m++)
                #pragma unroll
                for (int n = 0; n < 4; n++)
                    acc[m][n] = __builtin_amdgcn_mfma_f32_16x16x32_f16(af[m], bfr[n], acc[m][n], 0, 0, 0);
        }
        __syncthreads();
    }
    #pragma unroll
    for (int m = 0; m < 4; m++) {
        int row = rowbase + wm * 64 + m * 16 + lg * 4;
        #pragma unroll
        for (int n = 0; n < 4; n++) {
            int col = colbase + wn * 64 + n * 16 + l15;
            #pragma unroll
            for (int r = 0; r < 4; r++) {
                long idx = coff + (long)(row + r) * ldc + col;
                if (out_f32) ((float*)C0)[idx] = acc[m][n][r];
                else ((_Float16*)C0)[idx] = (_Float16)acc[m][n][r];
            }
        }
    }
}

// ---------------- fused attn v5: LDS-staged, two-pass, SINGLE-buffer ----------------
// 512 blocks (XCD-swizzled), 512 threads = 8 waves. Block: 32 t-rows x 1024 s
// of one (b,h). Waves (tw,sw): tw in {0,1} t-subtile, sw in {0..3} s-stripe.
// K chunk = 64 rows x 128 f16 (16 KB), staged with global_load_lds, linear LDS
// dest + inverse-XOR-swizzled global source + swizzled ds_read (m201 pattern).
// Proven sync: stage -> __syncthreads -> compute -> __syncthreads (gemm_bt's).
// Pass A: row sums of exp(QK^T*scale) -> rinv in LDS. Pass B: recompute,
// pbar += exp*rinv (rinv includes the 1/8 head mean), store f32 attn + f16 Pbar.

__device__ inline void stage_k32(char* lds, const _Float16* __restrict__ Kbuf,
                                 int b, int h, int i, int c, int tid) {
    const char* src = (const char*)(Kbuf + ((long)(i * 2 + b) * 1024 + c * 64) * 1024 + h * 128);
    int srow = tid >> 4;                     // 0..31
    int scolB = (tid & 15) << 4;             // byte col 0..240
    int gcolB = scolB ^ ((srow & 7) << 4);   // inverse swizzle on global source
    // rows 0..31 then 32..63 ((srow+32)&7 == srow&7, same swizzle)
    async16(lds + tid * 16, src + (long)srow * 2048 + gcolB);
    async16(lds + 8192 + tid * 16, src + (long)(srow + 32) * 2048 + gcolB);
}

__device__ inline void load_aq(f16x8* aq, const _Float16* __restrict__ Qbuf,
                               int b, int h, int i, int t0, int tw, int l15, int lg) {
    const _Float16* Qb = Qbuf + ((long)(i * 2 + b) * 1024 + t0 + tw * 16) * 1024 + h * 128;
    #pragma unroll
    for (int kk = 0; kk < 4; kk++)
        aq[kk] = *(const f16x8*)&Qb[(long)l15 * 1024 + kk * 32 + lg * 8];
}

__device__ inline f32x4 qk_tile(const char* kc, const f16x8* aq, int sw, int l15, int lg) {
    int brow = sw * 16 + l15;
    int swz = (brow & 7) << 4;
    f32x4 sv = {0.f, 0.f, 0.f, 0.f};
    #pragma unroll
    for (int kk = 0; kk < 4; kk++) {
        f16x8 bk = *(const f16x8*)(kc + brow * 256 + ((kk * 64 + lg * 16) ^ swz));
        sv = __builtin_amdgcn_mfma_f32_16x16x32_f16(aq[kk], bk, sv, 0, 0, 0);
    }
    return sv;
}

__global__ __launch_bounds__(512, 8) void attn_fused(
    const _Float16* __restrict__ Qbuf, const _Float16* __restrict__ Kbuf,
    float* __restrict__ attn_out, _Float16* __restrict__ Pbar)
{
    __shared__ _Float16 Kc[64 * 128];   // 16 KB single buffer
    __shared__ float rinv_lds[8][32];   // 1 KB
    __shared__ float red[8][16];        // 512 B
    int id = blockIdx.x;
    int orig = (id & 7) * 64 + (id >> 3);   // XCD k owns bh {2k,2k+1}
    int t0 = (orig & 31) * 32;
    int bh = orig >> 5, h = bh & 7, b = bh >> 3;
    int tid = threadIdx.x, wave = tid >> 6, lane = tid & 63;
    int l15 = lane & 15, lg = lane >> 4;
    int tw = wave >> 2, sw = wave & 3;
    const float scale = 0.088388347648318447f;  // 1/sqrt(128)
    char* kc = (char*)Kc;

    // ---- PASS A: row sums ----
    #pragma unroll 1
    for (int i = 0; i < 8; i++) {
        f16x8 aq[4];
        load_aq(aq, Qbuf, b, h, i, t0, tw, l15, lg);
        float rs[4] = {0.f, 0.f, 0.f, 0.f};
        #pragma unroll 1
        for (int c = 0; c < 16; c++) {
            stage_k32(kc, Kbuf, b, h, i, c, tid);
            __syncthreads();                       // drain: chunk ready
            f32x4 sv = qk_tile(kc, aq, sw, l15, lg);
            __syncthreads();                       // all reads done before next stage
            #pragma unroll
            for (int r = 0; r < 4; r++) rs[r] += __expf(sv[r] * scale);
        }
        #pragma unroll
        for (int off = 1; off < 16; off <<= 1)
            #pragma unroll
            for (int r = 0; r < 4; r++) rs[r] += __shfl_xor(rs[r], off, 64);
        if (l15 == 0) {
            #pragma unroll
            for (int r = 0; r < 4; r++) red[wave][lg * 4 + r] = rs[r];
        }
        __syncthreads();
        if (tid < 32) {
            int twq = tid >> 4, rr = tid & 15;
            float tot = red[twq * 4 + 0][rr] + red[twq * 4 + 1][rr]
                      + red[twq * 4 + 2][rr] + red[twq * 4 + 3][rr];
            rinv_lds[i][tid] = 0.125f / tot;
        }
        __syncthreads();
    }

    // ---- PASS B: recompute + accumulate mean attention ----
    #pragma unroll 1
    for (int c = 0; c < 16; c++) {
        float pbar[4] = {0.f, 0.f, 0.f, 0.f};
        #pragma unroll 1
        for (int i = 0; i < 8; i++) {
            f16x8 aq[4];
            load_aq(aq, Qbuf, b, h, i, t0, tw, l15, lg);
            stage_k32(kc, Kbuf, b, h, i, c, tid);
            __syncthreads();
            f32x4 sv = qk_tile(kc, aq, sw, l15, lg);
            __syncthreads();
            #pragma unroll
            for (int r = 0; r < 4; r++) {
                float rv = rinv_lds[i][tw * 16 + lg * 4 + r];
                pbar[r] += __expf(sv[r] * scale) * rv;
            }
        }
        long rbase = ((long)(bh * 1024 + t0 + tw * 16)) * 1024;
        int scol = c * 64 + sw * 16 + l15;
        #pragma unroll
        for (int r = 0; r < 4; r++) {
            long idx = rbase + (long)(lg * 4 + r) * 1024 + scol;
            attn_out[idx] = pbar[r];
            Pbar[idx] = (_Float16)pbar[r];
        }
    }
}

extern "C" void kernel_launch(void* const* d_in, const int* in_sizes, int n_in,
                              void* d_out, int out_size, void* d_ws, size_t ws_size,
                              hipStream_t stream) {
    const long M1 = 1048576;
    _Float16* ws = (_Float16*)d_ws;
    _Float16* q16  = ws;             // 2M elts
    _Float16* wq16 = ws + 6 * M1;    // 8M (Wk follows contiguously at +14M)
    _Float16* wv16 = ws + 22 * M1;   // 1M
    _Float16* wo16 = ws + 23 * M1;   // 1M
    _Float16* Qbuf = ws + 24 * M1;   // 16M (Kbuf follows at +40M)
    _Float16* Vbuf = ws + 56 * M1;   // 2M
    _Float16* Vt   = ws + 58 * M1;   // 2M
    _Float16* Pb   = ws + 60 * M1;   // 16M
    _Float16* Hbar = ws + 76 * M1;   // 2M
    float* out = (float*)d_out;
    float* attn_out = out + 2 * M1;

    // casts: query,key,value -> q16[0,2M,4M); Wq,Wk -> wq16 (16M); Wv,Wo
    cast_kernel<<<2048, 256, 0, stream>>>((const float*)d_in[0], q16, 2 * M1 / 4);
    cast_kernel<<<2048, 256, 0, stream>>>((const float*)d_in[1], q16 + 2 * M1, 2 * M1 / 4);
    cast_kernel<<<2048, 256, 0, stream>>>((const float*)d_in[2], q16 + 4 * M1, 2 * M1 / 4);
    cast_kernel<<<8192, 256, 0, stream>>>((const float*)d_in[3], wq16, 8 * M1 / 4);
    cast_kernel<<<8192, 256, 0, stream>>>((const float*)d_in[4], wq16 + 8 * M1, 8 * M1 / 4);
    cast_kernel<<<1024, 256, 0, stream>>>((const float*)d_in[5], wv16, M1 / 4);
    cast_kernel<<<1024, 256, 0, stream>>>((const float*)d_in[6], wo16, M1 / 4);

    // Q/K projections: z=0..7 -> Q_i = query @ Wq[i]^T; z=8..15 -> K_i
    gemm_bt<<<dim3(8, 16, 16), 256, 0, stream>>>(
        q16, wq16, Qbuf, 1024, 1024, 1024, 1024,
        /*az*/ 8, 2 * M1, 0, /*sb*/ M1,
        /*cz*/ 16, 0, 2 * M1, /*f32*/ 0);
    // V projection: value @ Wv^T
    gemm_bt<<<dim3(8, 16, 1), 256, 0, stream>>>(
        q16 + 4 * M1, wv16, Vbuf, 1024, 1024, 1024, 1024,
        1, 0, 0, 0, 1, 0, 0, 0);
    // V transpose -> Vt[b][e][s]
    transpose_v<<<dim3(16, 16, 2), 256, 0, stream>>>(Vbuf, Vt);
    // fused scores+softmax+mean_i -> attention (f32) + Pbar (f16)
    attn_fused<<<512, 512, 0, stream>>>(Qbuf, Qbuf + 16 * M1, attn_out, Pb);
    // PV: head[b][t][h*128+n] = sum_s Pbar[(b,h)][t][s] * Vt[b][h*128+n][s]
    gemm_bt<<<dim3(1, 8, 16), 256, 0, stream>>>(
        Pb, Vt, Hbar, 1024, 1024, 1024, 1024,
        /*az*/ 16, 0, M1, /*sb*/ M1 / 8,
        /*cz*/ 8, M1, 128, /*f32*/ 0);
    // out = head_mean @ Wo^T  (f32 out)
    gemm_bt<<<dim3(8, 16, 1), 256, 0, stream>>>(
        Hbar, wo16, out, 1024, 1024, 1024, 1024,
        1, 0, 0, 0, 1, 0, 0, /*f32*/ 1);
}

// Round 6
// 377.497 us; speedup vs baseline: 1.5812x; 1.5812x over previous
//
#include <hip/hip_runtime.h>
#include <hip/hip_bf16.h>

typedef _Float16 f16x8 __attribute__((ext_vector_type(8)));
typedef _Float16 f16x4 __attribute__((ext_vector_type(4)));
typedef float f32x4 __attribute__((ext_vector_type(4)));

typedef __attribute__((address_space(1))) void GV;
typedef __attribute__((address_space(3))) void LV;

__device__ inline void async16(void* lds, const void* g) {
    __builtin_amdgcn_global_load_lds((GV*)g, (LV*)lds, 16, 0, 0);
}

// ---------------- cast f32 -> f16 ----------------
__global__ __launch_bounds__(256) void cast_kernel(const float* __restrict__ in,
                                                   _Float16* __restrict__ out, long n4) {
    long i = (long)blockIdx.x * blockDim.x + threadIdx.x;
    if (i < n4) {
        float4 v = ((const float4*)in)[i];
        f16x4 o;
        o[0] = (_Float16)v.x; o[1] = (_Float16)v.y;
        o[2] = (_Float16)v.z; o[3] = (_Float16)v.w;
        ((f16x4*)out)[i] = o;
    }
}

// ---------------- V transpose: in [b][s][e] -> out [b][e][s] ----------------
__global__ __launch_bounds__(256) void transpose_v(const _Float16* __restrict__ in,
                                                   _Float16* __restrict__ out) {
    __shared__ _Float16 tile[64][66];
    int b = blockIdx.z;
    long base = (long)b * 1048576;
    int s0 = blockIdx.x * 64, e0 = blockIdx.y * 64;
    int tc = threadIdx.x & 63, tr = threadIdx.x >> 6;  // tr in 0..3
    #pragma unroll
    for (int rr = 0; rr < 64; rr += 4)
        tile[tr + rr][tc] = in[base + (long)(s0 + tr + rr) * 1024 + e0 + tc];
    __syncthreads();
    #pragma unroll
    for (int rr = 0; rr < 64; rr += 4)
        out[base + (long)(e0 + tr + rr) * 1024 + s0 + tc] = tile[tc][tr + rr];
}

// ---------------- batched GEMM: C = A @ B^T, f32 accum ----------------
__global__ __launch_bounds__(256) void gemm_bt(
    const _Float16* __restrict__ A0, const _Float16* __restrict__ B0, void* __restrict__ C0,
    int K, int lda, int ldb, int ldc,
    int az_div, long sa_hi, long sa_lo, long sb,
    int cz_div, long sc_hi, long sc_lo, int out_f32)
{
    __shared__ _Float16 As[128 * 64];
    __shared__ _Float16 Bs[128 * 64];
    int z = blockIdx.z;
    const _Float16* A = A0 + (long)(z / az_div) * sa_hi + (long)(z % az_div) * sa_lo;
    const _Float16* B = B0 + (long)z * sb;
    long coff = (long)(z / cz_div) * sc_hi + (long)(z % cz_div) * sc_lo;
    int rowbase = blockIdx.y * 128, colbase = blockIdx.x * 128;
    int t = threadIdx.x, wave = t >> 6, lane = t & 63;
    int l15 = lane & 15, lg = lane >> 4;
    int srow = t >> 3, scol = (t & 7) * 8;
    int wm = wave >> 1, wn = wave & 1;
    f32x4 acc[4][4] = {};
    for (int k0 = 0; k0 < K; k0 += 64) {
        #pragma unroll
        for (int ii = 0; ii < 4; ii++) {
            int r = srow + ii * 32;
            async16(&As[r * 64 + scol], A + (long)(rowbase + r) * lda + k0 + scol);
            async16(&Bs[r * 64 + scol], B + (long)(colbase + r) * ldb + k0 + scol);
        }
        __syncthreads();
        #pragma unroll
        for (int ks = 0; ks < 2; ks++) {
            f16x8 af[4], bfr[4];
            #pragma unroll
            for (int m = 0; m < 4; m++)
                af[m] = *(const f16x8*)&As[(wm * 64 + m * 16 + l15) * 64 + ks * 32 + lg * 8];
            #pragma unroll
            for (int n = 0; n < 4; n++)
                bfr[n] = *(const f16x8*)&Bs[(wn * 64 + n * 16 + l15) * 64 + ks * 32 + lg * 8];
            #pragma unroll
            for (int m = 0; m < 4; m++)
                #pragma unroll
                for (int n = 0; n < 4; n++)
                    acc[m][n] = __builtin_amdgcn_mfma_f32_16x16x32_f16(af[m], bfr[n], acc[m][n], 0, 0, 0);
        }
        __syncthreads();
    }
    #pragma unroll
    for (int m = 0; m < 4; m++) {
        int row = rowbase + wm * 64 + m * 16 + lg * 4;
        #pragma unroll
        for (int n = 0; n < 4; n++) {
            int col = colbase + wn * 64 + n * 16 + l15;
            #pragma unroll
            for (int r = 0; r < 4; r++) {
                long idx = coff + (long)(row + r) * ldc + col;
                if (out_f32) ((float*)C0)[idx] = acc[m][n][r];
                else ((_Float16*)C0)[idx] = (_Float16)acc[m][n][r];
            }
        }
    }
}

// ---------------- fused attn v6: single-pass, exp kept in registers ----------------
// 1024 blocks (XCD-swizzled: XCD k owns bh {2k,2k+1}), 512 threads = 8 waves.
// Block: 16 t-rows x all 1024 s of one (b,h). Wave (cw,sw): cw in {0,1} picks
// 64-row half of the staged 128-row K chunk, sw in {0..3} the 16-col subtile.
// Per head i: aq loaded ONCE; 8 chunk-steps {stage 32KB -> sync -> 4 MFMA ->
// sync -> exp into s[c][r], rs += }; one cross-wave sum reduction -> rinv;
// acc[c][r] += s[c][r]*rinv. After 8 heads, store attn f32 + Pbar f16.
// Sync pattern identical to the passing v5 (stage->sync->compute->sync).

__device__ inline void stage_k128(char* lds, const _Float16* __restrict__ Kbuf,
                                  int b, int h, int i, int c, int tid) {
    const char* src = (const char*)(Kbuf + ((long)(i * 2 + b) * 1024 + c * 128) * 1024 + h * 128);
    int srow = tid >> 4;                     // 0..31
    int scolB = (tid & 15) << 4;             // byte col 0..240
    int gcolB = scolB ^ ((srow & 7) << 4);   // inverse swizzle on global source
    #pragma unroll
    for (int j = 0; j < 4; j++) {            // rows srow, +32, +64, +96 (same &7)
        int row = srow + 32 * j;
        async16(lds + row * 256 + scolB, src + (long)row * 2048 + gcolB);
    }
}

__device__ inline void load_aq(f16x8* aq, const _Float16* __restrict__ Qbuf,
                               int b, int h, int i, int t0, int l15, int lg) {
    const _Float16* Qb = Qbuf + ((long)(i * 2 + b) * 1024 + t0) * 1024 + h * 128;
    #pragma unroll
    for (int kk = 0; kk < 4; kk++)
        aq[kk] = *(const f16x8*)&Qb[(long)l15 * 1024 + kk * 32 + lg * 8];
}

__device__ inline f32x4 qk_tile(const char* kc, const f16x8* aq, int brow, int l15, int lg) {
    int swz = (brow & 7) << 4;
    f32x4 sv = {0.f, 0.f, 0.f, 0.f};
    #pragma unroll
    for (int kk = 0; kk < 4; kk++) {
        f16x8 bk = *(const f16x8*)(kc + brow * 256 + ((kk * 64 + lg * 16) ^ swz));
        sv = __builtin_amdgcn_mfma_f32_16x16x32_f16(aq[kk], bk, sv, 0, 0, 0);
    }
    return sv;
}

__global__ __launch_bounds__(512, 4) void attn_fused(
    const _Float16* __restrict__ Qbuf, const _Float16* __restrict__ Kbuf,
    float* __restrict__ attn_out, _Float16* __restrict__ Pbar)
{
    __shared__ _Float16 Kc[128 * 128];  // 32 KB single buffer
    __shared__ float red[8][16];        // 512 B
    int id = blockIdx.x;
    int orig = (id & 7) * 128 + (id >> 3);   // XCD k owns bh {2k,2k+1}
    int t0 = (orig & 63) * 16;
    int bh = orig >> 6, h = bh & 7, b = bh >> 3;
    int tid = threadIdx.x, wave = tid >> 6, lane = tid & 63;
    int l15 = lane & 15, lg = lane >> 4;
    int cw = wave >> 2, sw = wave & 3;
    int brow = cw * 64 + sw * 16 + l15;      // row within staged 128-row chunk
    const float scale = 0.088388347648318447f;  // 1/sqrt(128)
    char* kc = (char*)Kc;
    float acc[8][4] = {};

    #pragma unroll 1
    for (int i = 0; i < 8; i++) {
        f16x8 aq[4];
        load_aq(aq, Qbuf, b, h, i, t0, l15, lg);
        float s[8][4];
        float rs[4] = {0.f, 0.f, 0.f, 0.f};
        #pragma unroll
        for (int c = 0; c < 8; c++) {
            stage_k128(kc, Kbuf, b, h, i, c, tid);
            __syncthreads();                       // chunk ready
            f32x4 sv = qk_tile(kc, aq, brow, l15, lg);
            __syncthreads();                       // reads done before next stage
            #pragma unroll
            for (int r = 0; r < 4; r++) {
                float e = __expf(sv[r] * scale);
                s[c][r] = e;
                rs[r] += e;
            }
        }
        // row-sum reduce: across l15 lanes, then across all 8 waves
        #pragma unroll
        for (int off = 1; off < 16; off <<= 1)
            #pragma unroll
            for (int r = 0; r < 4; r++) rs[r] += __shfl_xor(rs[r], off, 64);
        if (l15 == 0) {
            #pragma unroll
            for (int r = 0; r < 4; r++) red[wave][lg * 4 + r] = rs[r];
        }
        __syncthreads();
        #pragma unroll
        for (int r = 0; r < 4; r++) {
            int row = lg * 4 + r;
            float tot = red[0][row] + red[1][row] + red[2][row] + red[3][row]
                      + red[4][row] + red[5][row] + red[6][row] + red[7][row];
            float rinv = 0.125f / tot;
            #pragma unroll
            for (int c = 0; c < 8; c++) acc[c][r] += s[c][r] * rinv;
        }
        __syncthreads();   // red reads done before next i's writes
    }

    long rbase = ((long)(bh * 1024 + t0)) * 1024;
    #pragma unroll
    for (int c = 0; c < 8; c++) {
        int scol = c * 128 + cw * 64 + sw * 16 + l15;
        #pragma unroll
        for (int r = 0; r < 4; r++) {
            long idx = rbase + (long)(lg * 4 + r) * 1024 + scol;
            attn_out[idx] = acc[c][r];
            Pbar[idx] = (_Float16)acc[c][r];
        }
    }
}

extern "C" void kernel_launch(void* const* d_in, const int* in_sizes, int n_in,
                              void* d_out, int out_size, void* d_ws, size_t ws_size,
                              hipStream_t stream) {
    const long M1 = 1048576;
    _Float16* ws = (_Float16*)d_ws;
    _Float16* q16  = ws;             // 2M elts
    _Float16* wq16 = ws + 6 * M1;    // 8M (Wk follows contiguously at +14M)
    _Float16* wv16 = ws + 22 * M1;   // 1M
    _Float16* wo16 = ws + 23 * M1;   // 1M
    _Float16* Qbuf = ws + 24 * M1;   // 16M (Kbuf follows at +40M)
    _Float16* Vbuf = ws + 56 * M1;   // 2M
    _Float16* Vt   = ws + 58 * M1;   // 2M
    _Float16* Pb   = ws + 60 * M1;   // 16M
    _Float16* Hbar = ws + 76 * M1;   // 2M
    float* out = (float*)d_out;
    float* attn_out = out + 2 * M1;

    // casts: query,key,value -> q16[0,2M,4M); Wq,Wk -> wq16 (16M); Wv,Wo
    cast_kernel<<<2048, 256, 0, stream>>>((const float*)d_in[0], q16, 2 * M1 / 4);
    cast_kernel<<<2048, 256, 0, stream>>>((const float*)d_in[1], q16 + 2 * M1, 2 * M1 / 4);
    cast_kernel<<<2048, 256, 0, stream>>>((const float*)d_in[2], q16 + 4 * M1, 2 * M1 / 4);
    cast_kernel<<<8192, 256, 0, stream>>>((const float*)d_in[3], wq16, 8 * M1 / 4);
    cast_kernel<<<8192, 256, 0, stream>>>((const float*)d_in[4], wq16 + 8 * M1, 8 * M1 / 4);
    cast_kernel<<<1024, 256, 0, stream>>>((const float*)d_in[5], wv16, M1 / 4);
    cast_kernel<<<1024, 256, 0, stream>>>((const float*)d_in[6], wo16, M1 / 4);

    // Q/K projections: z=0..7 -> Q_i = query @ Wq[i]^T; z=8..15 -> K_i
    gemm_bt<<<dim3(8, 16, 16), 256, 0, stream>>>(
        q16, wq16, Qbuf, 1024, 1024, 1024, 1024,
        /*az*/ 8, 2 * M1, 0, /*sb*/ M1,
        /*cz*/ 16, 0, 2 * M1, /*f32*/ 0);
    // V projection: value @ Wv^T
    gemm_bt<<<dim3(8, 16, 1), 256, 0, stream>>>(
        q16 + 4 * M1, wv16, Vbuf, 1024, 1024, 1024, 1024,
        1, 0, 0, 0, 1, 0, 0, 0);
    // V transpose -> Vt[b][e][s]
    transpose_v<<<dim3(16, 16, 2), 256, 0, stream>>>(Vbuf, Vt);
    // fused scores+softmax+mean_i -> attention (f32) + Pbar (f16)
    attn_fused<<<1024, 512, 0, stream>>>(Qbuf, Qbuf + 16 * M1, attn_out, Pb);
    // PV: head[b][t][h*128+n] = sum_s Pbar[(b,h)][t][s] * Vt[b][h*128+n][s]
    gemm_bt<<<dim3(1, 8, 16), 256, 0, stream>>>(
        Pb, Vt, Hbar, 1024, 1024, 1024, 1024,
        /*az*/ 16, 0, M1, /*sb*/ M1 / 8,
        /*cz*/ 8, M1, 128, /*f32*/ 0);
    // out = head_mean @ Wo^T  (f32 out)
    gemm_bt<<<dim3(8, 16, 1), 256, 0, stream>>>(
        Hbar, wo16, out, 1024, 1024, 1024, 1024,
        1, 0, 0, 0, 1, 0, 0, /*f32*/ 1);
}

// Round 7
// 350.887 us; speedup vs baseline: 1.7011x; 1.0758x over previous
//
#include <hip/hip_runtime.h>
#include <hip/hip_bf16.h>

typedef _Float16 f16x8 __attribute__((ext_vector_type(8)));
typedef _Float16 f16x4 __attribute__((ext_vector_type(4)));
typedef float f32x4 __attribute__((ext_vector_type(4)));

typedef __attribute__((address_space(1))) void GV;
typedef __attribute__((address_space(3))) void LV;

__device__ inline void async16(void* lds, const void* g) {
    __builtin_amdgcn_global_load_lds((GV*)g, (LV*)lds, 16, 0, 0);
}

// ---------------- cast f32 -> f16 ----------------
__global__ __launch_bounds__(256) void cast_kernel(const float* __restrict__ in,
                                                   _Float16* __restrict__ out, long n4) {
    long i = (long)blockIdx.x * blockDim.x + threadIdx.x;
    if (i < n4) {
        float4 v = ((const float4*)in)[i];
        f16x4 o;
        o[0] = (_Float16)v.x; o[1] = (_Float16)v.y;
        o[2] = (_Float16)v.z; o[3] = (_Float16)v.w;
        ((f16x4*)out)[i] = o;
    }
}

// ---------------- V transpose: in [b][s][e] -> out [b][e][s] ----------------
__global__ __launch_bounds__(256) void transpose_v(const _Float16* __restrict__ in,
                                                   _Float16* __restrict__ out) {
    __shared__ _Float16 tile[64][66];
    int b = blockIdx.z;
    long base = (long)b * 1048576;
    int s0 = blockIdx.x * 64, e0 = blockIdx.y * 64;
    int tc = threadIdx.x & 63, tr = threadIdx.x >> 6;  // tr in 0..3
    #pragma unroll
    for (int rr = 0; rr < 64; rr += 4)
        tile[tr + rr][tc] = in[base + (long)(s0 + tr + rr) * 1024 + e0 + tc];
    __syncthreads();
    #pragma unroll
    for (int rr = 0; rr < 64; rr += 4)
        out[base + (long)(e0 + tr + rr) * 1024 + s0 + tc] = tile[tc][tr + rr];
}

// ---------------- batched GEMM: C = A @ B^T, f32 accum ----------------
// RB = row-fragments per wave: tile M = RB*32 (RB=4 -> 128, RB=2 -> 64).
template<int RB>
__global__ __launch_bounds__(256) void gemm_bt(
    const _Float16* __restrict__ A0, const _Float16* __restrict__ B0, void* __restrict__ C0,
    int K, int lda, int ldb, int ldc,
    int az_div, long sa_hi, long sa_lo, long sb,
    int cz_div, long sc_hi, long sc_lo, int out_f32)
{
    __shared__ _Float16 As[RB * 32 * 64];
    __shared__ _Float16 Bs[128 * 64];
    int z = blockIdx.z;
    const _Float16* A = A0 + (long)(z / az_div) * sa_hi + (long)(z % az_div) * sa_lo;
    const _Float16* B = B0 + (long)z * sb;
    long coff = (long)(z / cz_div) * sc_hi + (long)(z % cz_div) * sc_lo;
    int rowbase = blockIdx.y * (RB * 32), colbase = blockIdx.x * 128;
    int t = threadIdx.x, wave = t >> 6, lane = t & 63;
    int l15 = lane & 15, lg = lane >> 4;
    int srow = t >> 3, scol = (t & 7) * 8;
    int wm = wave >> 1, wn = wave & 1;
    f32x4 acc[RB][4] = {};
    for (int k0 = 0; k0 < K; k0 += 64) {
        #pragma unroll
        for (int ii = 0; ii < RB; ii++) {
            int r = srow + ii * 32;
            async16(&As[r * 64 + scol], A + (long)(rowbase + r) * lda + k0 + scol);
        }
        #pragma unroll
        for (int ii = 0; ii < 4; ii++) {
            int r = srow + ii * 32;
            async16(&Bs[r * 64 + scol], B + (long)(colbase + r) * ldb + k0 + scol);
        }
        __syncthreads();
        #pragma unroll
        for (int ks = 0; ks < 2; ks++) {
            f16x8 af[RB], bfr[4];
            #pragma unroll
            for (int m = 0; m < RB; m++)
                af[m] = *(const f16x8*)&As[(wm * (RB * 16) + m * 16 + l15) * 64 + ks * 32 + lg * 8];
            #pragma unroll
            for (int n = 0; n < 4; n++)
                bfr[n] = *(const f16x8*)&Bs[(wn * 64 + n * 16 + l15) * 64 + ks * 32 + lg * 8];
            #pragma unroll
            for (int m = 0; m < RB; m++)
                #pragma unroll
                for (int n = 0; n < 4; n++)
                    acc[m][n] = __builtin_amdgcn_mfma_f32_16x16x32_f16(af[m], bfr[n], acc[m][n], 0, 0, 0);
        }
        __syncthreads();
    }
    #pragma unroll
    for (int m = 0; m < RB; m++) {
        int row = rowbase + wm * (RB * 16) + m * 16 + lg * 4;
        #pragma unroll
        for (int n = 0; n < 4; n++) {
            int col = colbase + wn * 64 + n * 16 + l15;
            #pragma unroll
            for (int r = 0; r < 4; r++) {
                long idx = coff + (long)(row + r) * ldc + col;
                if (out_f32) ((float*)C0)[idx] = acc[m][n][r];
                else ((_Float16*)C0)[idx] = (_Float16)acc[m][n][r];
            }
        }
    }
}

// ---------------- fused attn v7: single-pass, DOUBLE-buffered staging ----------------
// 1024 blocks (XCD-swizzled), 512 threads = 8 waves; block = 16 t-rows x 1024 s
// of one (b,h). 64 linearized chunk-steps m=i*8+c; buffers alternate on c&1.
// T3-minimal pattern: {barrier(drain m) -> issue stage(m+1, buf^1) -> compute m}.
// Reads of buf[(m+1)&1] finished in step m-1 before barrier m => DMA write safe.

__device__ inline void stage_k128(char* lds, const _Float16* __restrict__ Kbuf,
                                  int b, int h, int i, int c, int tid) {
    const char* src = (const char*)(Kbuf + ((long)(i * 2 + b) * 1024 + c * 128) * 1024 + h * 128);
    int srow = tid >> 4;                     // 0..31
    int scolB = (tid & 15) << 4;             // byte col 0..240
    int gcolB = scolB ^ ((srow & 7) << 4);   // inverse swizzle on global source
    #pragma unroll
    for (int j = 0; j < 4; j++) {            // rows srow, +32, +64, +96 (same &7)
        int row = srow + 32 * j;
        async16(lds + row * 256 + scolB, src + (long)row * 2048 + gcolB);
    }
}

__device__ inline void load_aq(f16x8* aq, const _Float16* __restrict__ Qbuf,
                               int b, int h, int i, int t0, int l15, int lg) {
    const _Float16* Qb = Qbuf + ((long)(i * 2 + b) * 1024 + t0) * 1024 + h * 128;
    #pragma unroll
    for (int kk = 0; kk < 4; kk++)
        aq[kk] = *(const f16x8*)&Qb[(long)l15 * 1024 + kk * 32 + lg * 8];
}

__device__ inline f32x4 qk_tile(const char* kc, const f16x8* aq, int brow, int l15, int lg) {
    int swz = (brow & 7) << 4;
    f32x4 sv = {0.f, 0.f, 0.f, 0.f};
    #pragma unroll
    for (int kk = 0; kk < 4; kk++) {
        f16x8 bk = *(const f16x8*)(kc + brow * 256 + ((kk * 64 + lg * 16) ^ swz));
        sv = __builtin_amdgcn_mfma_f32_16x16x32_f16(aq[kk], bk, sv, 0, 0, 0);
    }
    return sv;
}

__global__ __launch_bounds__(512, 4) void attn_fused(
    const _Float16* __restrict__ Qbuf, const _Float16* __restrict__ Kbuf,
    float* __restrict__ attn_out, _Float16* __restrict__ Pbar)
{
    __shared__ _Float16 Kc[2][128 * 128];  // 2 x 32 KB
    __shared__ float red[8][16];           // 512 B
    int id = blockIdx.x;
    int orig = (id & 7) * 128 + (id >> 3);   // XCD k owns bh {2k,2k+1}
    int t0 = (orig & 63) * 16;
    int bh = orig >> 6, h = bh & 7, b = bh >> 3;
    int tid = threadIdx.x, wave = tid >> 6, lane = tid & 63;
    int l15 = lane & 15, lg = lane >> 4;
    int cw = wave >> 2, sw = wave & 3;
    int brow = cw * 64 + sw * 16 + l15;      // row within staged 128-row chunk
    const float scale = 0.088388347648318447f;  // 1/sqrt(128)
    float acc[8][4] = {};

    stage_k128((char*)Kc[0], Kbuf, b, h, 0, 0, tid);  // prologue: step 0

    #pragma unroll 1
    for (int i = 0; i < 8; i++) {
        f16x8 aq[4];
        load_aq(aq, Qbuf, b, h, i, t0, l15, lg);
        float s[8][4];
        float rs[4] = {0.f, 0.f, 0.f, 0.f};
        #pragma unroll
        for (int c = 0; c < 8; c++) {
            int m = i * 8 + c;
            __syncthreads();   // drain stage(m); all reads of buf[(m+1)&1] are done
            if (m < 63)
                stage_k128((char*)Kc[(c + 1) & 1], Kbuf, b, h, (m + 1) >> 3, (m + 1) & 7, tid);
            f32x4 sv = qk_tile((const char*)Kc[c & 1], aq, brow, l15, lg);
            #pragma unroll
            for (int r = 0; r < 4; r++) {
                float e = __expf(sv[r] * scale);
                s[c][r] = e;
                rs[r] += e;
            }
        }
        // row-sum reduce: across l15 lanes, then across all 8 waves
        #pragma unroll
        for (int off = 1; off < 16; off <<= 1)
            #pragma unroll
            for (int r = 0; r < 4; r++) rs[r] += __shfl_xor(rs[r], off, 64);
        if (l15 == 0) {
            #pragma unroll
            for (int r = 0; r < 4; r++) red[wave][lg * 4 + r] = rs[r];
        }
        __syncthreads();
        #pragma unroll
        for (int r = 0; r < 4; r++) {
            int row = lg * 4 + r;
            float tot = red[0][row] + red[1][row] + red[2][row] + red[3][row]
                      + red[4][row] + red[5][row] + red[6][row] + red[7][row];
            float rinv = 0.125f / tot;
            #pragma unroll
            for (int c = 0; c < 8; c++) acc[c][r] += s[c][r] * rinv;
        }
        __syncthreads();   // red reads done before next i's writes
    }

    long rbase = ((long)(bh * 1024 + t0)) * 1024;
    #pragma unroll
    for (int c = 0; c < 8; c++) {
        int scol = c * 128 + cw * 64 + sw * 16 + l15;
        #pragma unroll
        for (int r = 0; r < 4; r++) {
            long idx = rbase + (long)(lg * 4 + r) * 1024 + scol;
            attn_out[idx] = acc[c][r];
            Pbar[idx] = (_Float16)acc[c][r];
        }
    }
}

extern "C" void kernel_launch(void* const* d_in, const int* in_sizes, int n_in,
                              void* d_out, int out_size, void* d_ws, size_t ws_size,
                              hipStream_t stream) {
    const long M1 = 1048576;
    _Float16* ws = (_Float16*)d_ws;
    _Float16* q16  = ws;             // 2M elts (query; key at +2M, value at +4M)
    _Float16* wq16 = ws + 6 * M1;    // 8M (Wk at +8M, Wv at +16M -> contiguous for z-indexed B)
    _Float16* wv16 = ws + 22 * M1;   // 1M  (== wq16 + 16M)
    _Float16* wo16 = ws + 23 * M1;   // 1M
    _Float16* Qbuf = ws + 24 * M1;   // 16M (Kbuf at +16M, Vbuf at +32M)
    _Float16* Vbuf = ws + 56 * M1;   // 2M  (== Qbuf + 32M)
    _Float16* Vt   = ws + 58 * M1;   // 2M
    _Float16* Pb   = ws + 60 * M1;   // 16M
    _Float16* Hbar = ws + 76 * M1;   // 2M
    float* out = (float*)d_out;
    float* attn_out = out + 2 * M1;

    // casts: query,key,value -> q16[0,2M,4M); Wq,Wk -> wq16 (16M); Wv,Wo
    cast_kernel<<<2048, 256, 0, stream>>>((const float*)d_in[0], q16, 2 * M1 / 4);
    cast_kernel<<<2048, 256, 0, stream>>>((const float*)d_in[1], q16 + 2 * M1, 2 * M1 / 4);
    cast_kernel<<<2048, 256, 0, stream>>>((const float*)d_in[2], q16 + 4 * M1, 2 * M1 / 4);
    cast_kernel<<<8192, 256, 0, stream>>>((const float*)d_in[3], wq16, 8 * M1 / 4);
    cast_kernel<<<8192, 256, 0, stream>>>((const float*)d_in[4], wq16 + 8 * M1, 8 * M1 / 4);
    cast_kernel<<<1024, 256, 0, stream>>>((const float*)d_in[5], wv16, M1 / 4);
    cast_kernel<<<1024, 256, 0, stream>>>((const float*)d_in[6], wo16, M1 / 4);

    // Projections, one dispatch: z=0..7 Q_i = query @ Wq[i]^T; z=8..15 K_i;
    // z=16 V = value @ Wv^T (A via z/8: query,key,value; B=wq16+16M=wv16;
    // C via z/16: sc_hi=32M -> Vbuf).
    gemm_bt<4><<<dim3(8, 16, 17), 256, 0, stream>>>(
        q16, wq16, Qbuf, 1024, 1024, 1024, 1024,
        /*az*/ 8, 2 * M1, 0, /*sb*/ M1,
        /*cz*/ 16, 32 * M1, 2 * M1, /*f32*/ 0);
    // V transpose -> Vt[b][e][s]
    transpose_v<<<dim3(16, 16, 2), 256, 0, stream>>>(Vbuf, Vt);
    // fused scores+softmax+mean_i -> attention (f32) + Pbar (f16)
    attn_fused<<<1024, 512, 0, stream>>>(Qbuf, Qbuf + 16 * M1, attn_out, Pb);
    // PV: head[b][t][h*128+n] = sum_s Pbar[(b,h)][t][s] * Vt[b][h*128+n][s]
    gemm_bt<2><<<dim3(1, 16, 16), 256, 0, stream>>>(
        Pb, Vt, Hbar, 1024, 1024, 1024, 1024,
        /*az*/ 16, 0, M1, /*sb*/ M1 / 8,
        /*cz*/ 8, M1, 128, /*f32*/ 0);
    // out = head_mean @ Wo^T  (f32 out)
    gemm_bt<2><<<dim3(8, 32, 1), 256, 0, stream>>>(
        Hbar, wo16, out, 1024, 1024, 1024, 1024,
        1, 0, 0, 0, 1, 0, 0, /*f32*/ 1);
}

// Round 8
// 336.661 us; speedup vs baseline: 1.7730x; 1.0423x over previous
//
#include <hip/hip_runtime.h>
#include <hip/hip_bf16.h>

typedef _Float16 f16x8 __attribute__((ext_vector_type(8)));
typedef _Float16 f16x4 __attribute__((ext_vector_type(4)));
typedef float f32x4 __attribute__((ext_vector_type(4)));

typedef __attribute__((address_space(1))) void GV;
typedef __attribute__((address_space(3))) void LV;

__device__ inline void async16(void* lds, const void* g) {
    __builtin_amdgcn_global_load_lds((GV*)g, (LV*)lds, 16, 0, 0);
}

// ---------------- fused cast f32 -> f16 for all 7 inputs ----------------
__global__ __launch_bounds__(256) void cast_all(
    const float* __restrict__ q, const float* __restrict__ k, const float* __restrict__ v,
    const float* __restrict__ wq, const float* __restrict__ wk,
    const float* __restrict__ wv, const float* __restrict__ wo, _Float16* __restrict__ ws)
{
    const long M1 = 1048576;
    const long tot = 6291456;  // total float4s
    for (long idx = (long)blockIdx.x * 256 + threadIdx.x; idx < tot;
         idx += (long)gridDim.x * 256) {
        const float* src; long local; long doff;
        if (idx < 1572864) {                    // q,k,v: 512K f4 each
            int seg = (int)(idx >> 19);
            src = seg == 0 ? q : (seg == 1 ? k : v);
            local = idx & 524287; doff = (long)seg * 2 * M1;
        } else if (idx < 5767168) {             // wq, wk: 2M f4 each
            int seg = (int)((idx - 1572864) >> 21);
            src = seg == 0 ? wq : wk;
            local = (idx - 1572864) & 2097151; doff = (6 + 8 * (long)seg) * M1;
        } else {                                 // wv, wo: 256K f4 each
            int seg = (int)((idx - 5767168) >> 18);
            src = seg == 0 ? wv : wo;
            local = (idx - 5767168) & 262143; doff = (22 + (long)seg) * M1;
        }
        float4 val = ((const float4*)src)[local];
        f16x4 o;
        o[0] = (_Float16)val.x; o[1] = (_Float16)val.y;
        o[2] = (_Float16)val.z; o[3] = (_Float16)val.w;
        *(f16x4*)&ws[doff + 4 * local] = o;
    }
}

// ---------------- V transpose: in [b][s][e] -> out [b][e][s] ----------------
__global__ __launch_bounds__(256) void transpose_v(const _Float16* __restrict__ in,
                                                   _Float16* __restrict__ out) {
    __shared__ _Float16 tile[64][66];
    int b = blockIdx.z;
    long base = (long)b * 1048576;
    int s0 = blockIdx.x * 64, e0 = blockIdx.y * 64;
    int tc = threadIdx.x & 63, tr = threadIdx.x >> 6;
    #pragma unroll
    for (int rr = 0; rr < 64; rr += 4)
        tile[tr + rr][tc] = in[base + (long)(s0 + tr + rr) * 1024 + e0 + tc];
    __syncthreads();
    #pragma unroll
    for (int rr = 0; rr < 64; rr += 4)
        out[base + (long)(e0 + tr + rr) * 1024 + s0 + tc] = tile[tc][tr + rr];
}

// ---------------- batched GEMM: C = A @ B^T, f32 accum ----------------
// RB = row-fragments per wave (tile M = RB*32). XS = 1: flat-grid XCD-chunk
// swizzle — each XCD owns (z, y-half) chunks of 64 blocks so its L2 working
// set is A-half (2MB) + B panel (2MB) = 4MB = L2 capacity.
template<int RB, int XS>
__global__ __launch_bounds__(256) void gemm_bt(
    const _Float16* __restrict__ A0, const _Float16* __restrict__ B0, void* __restrict__ C0,
    int K, int lda, int ldb, int ldc,
    int az_div, long sa_hi, long sa_lo, long sb,
    int cz_div, long sc_hi, long sc_lo, int out_f32)
{
    __shared__ _Float16 As[RB * 32 * 64];
    __shared__ _Float16 Bs[128 * 64];
    int bx, by, bz;
    if (XS) {
        int p = blockIdx.x;
        int xcd = p & 7, s = p >> 3;
        int c, within;
        if (s < 256) { c = xcd + 8 * (s >> 6); within = s & 63; }
        else         { c = 32 + (xcd >> 2); within = (xcd & 3) * 16 + (s - 256); }
        bz = c >> 1;
        by = (c & 1) * 8 + (within >> 3);
        bx = within & 7;
    } else { bx = blockIdx.x; by = blockIdx.y; bz = blockIdx.z; }
    int z = bz;
    const _Float16* A = A0 + (long)(z / az_div) * sa_hi + (long)(z % az_div) * sa_lo;
    const _Float16* B = B0 + (long)z * sb;
    long coff = (long)(z / cz_div) * sc_hi + (long)(z % cz_div) * sc_lo;
    int rowbase = by * (RB * 32), colbase = bx * 128;
    int t = threadIdx.x, wave = t >> 6, lane = t & 63;
    int l15 = lane & 15, lg = lane >> 4;
    int srow = t >> 3, scol = (t & 7) * 8;
    int wm = wave >> 1, wn = wave & 1;
    f32x4 acc[RB][4] = {};
    for (int k0 = 0; k0 < K; k0 += 64) {
        #pragma unroll
        for (int ii = 0; ii < RB; ii++) {
            int r = srow + ii * 32;
            async16(&As[r * 64 + scol], A + (long)(rowbase + r) * lda + k0 + scol);
        }
        #pragma unroll
        for (int ii = 0; ii < 4; ii++) {
            int r = srow + ii * 32;
            async16(&Bs[r * 64 + scol], B + (long)(colbase + r) * ldb + k0 + scol);
        }
        __syncthreads();
        #pragma unroll
        for (int ks = 0; ks < 2; ks++) {
            f16x8 af[RB], bfr[4];
            #pragma unroll
            for (int m = 0; m < RB; m++)
                af[m] = *(const f16x8*)&As[(wm * (RB * 16) + m * 16 + l15) * 64 + ks * 32 + lg * 8];
            #pragma unroll
            for (int n = 0; n < 4; n++)
                bfr[n] = *(const f16x8*)&Bs[(wn * 64 + n * 16 + l15) * 64 + ks * 32 + lg * 8];
            #pragma unroll
            for (int m = 0; m < RB; m++)
                #pragma unroll
                for (int n = 0; n < 4; n++)
                    acc[m][n] = __builtin_amdgcn_mfma_f32_16x16x32_f16(af[m], bfr[n], acc[m][n], 0, 0, 0);
        }
        __syncthreads();
    }
    #pragma unroll
    for (int m = 0; m < RB; m++) {
        int row = rowbase + wm * (RB * 16) + m * 16 + lg * 4;
        #pragma unroll
        for (int n = 0; n < 4; n++) {
            int col = colbase + wn * 64 + n * 16 + l15;
            #pragma unroll
            for (int r = 0; r < 4; r++) {
                long idx = coff + (long)(row + r) * ldc + col;
                if (out_f32) ((float*)C0)[idx] = acc[m][n][r];
                else ((_Float16*)C0)[idx] = (_Float16)acc[m][n][r];
            }
        }
    }
}

// ---------------- fused attn v8: v7 structure + hoisted affine pointers ----------------
// 1024 blocks (XCD-swizzled), 512 threads = 8 waves; block = 16 t-rows x 1024 s
// of one (b,h). 64 linearized chunk-steps m=i*8+c; buffers alternate on c&1.
// {barrier(drain m) -> issue stage(m+1, buf^1) -> compute m}. All stage/Q/read
// addresses are per-thread bases + affine increments (no per-step recompute).
__global__ __launch_bounds__(512, 4) void attn_fused(
    const _Float16* __restrict__ Qbuf, const _Float16* __restrict__ Kbuf,
    float* __restrict__ attn_out, _Float16* __restrict__ Pbar)
{
    __shared__ _Float16 Kc[2][128 * 128];  // 2 x 32 KB
    __shared__ float red[8][16];
    int id = blockIdx.x;
    int orig = (id & 7) * 128 + (id >> 3);   // XCD k owns bh {2k,2k+1}
    int t0 = (orig & 63) * 16;
    int bh = orig >> 6, h = bh & 7, b = bh >> 3;
    int tid = threadIdx.x, wave = tid >> 6, lane = tid & 63;
    int l15 = lane & 15, lg = lane >> 4;
    int cw = wave >> 2, sw = wave & 3;
    int brow = cw * 64 + sw * 16 + l15;
    const float scale = 0.088388347648318447f;  // 1/sqrt(128)
    float acc[8][4] = {};

    // hoisted per-thread bases
    int srow = tid >> 4;
    int scolB = (tid & 15) << 4;
    int gcolB = scolB ^ ((srow & 7) << 4);    // inverse swizzle on global source
    int ldsoff = srow * 256 + scolB;
    const char* pk = (const char*)(Kbuf + (long)b * 1048576 + h * 128)
                     + (long)srow * 2048 + gcolB;
    const char* pq = (const char*)(Qbuf + ((long)(b * 1024 + t0 + l15)) * 1024 + h * 128)
                     + lg * 16;
    int swz = (brow & 7) << 4;
    int rdoff[4];
    #pragma unroll
    for (int kk = 0; kk < 4; kk++)
        rdoff[kk] = brow * 256 + ((kk * 64 + lg * 16) ^ swz);

    // prologue: stage step 0 into buf 0
    {
        char* lb = (char*)Kc[0] + ldsoff;
        #pragma unroll
        for (int j = 0; j < 4; j++)
            async16(lb + j * 8192, pk + (long)j * 65536);
    }

    #pragma unroll 1
    for (int i = 0; i < 8; i++) {
        f16x8 aq[4];
        #pragma unroll
        for (int kk = 0; kk < 4; kk++)
            aq[kk] = *(const f16x8*)(pq + kk * 64);
        pq += 4194304;   // next i (+2M f16)
        float s[8][4];
        float rs[4] = {0.f, 0.f, 0.f, 0.f};
        #pragma unroll
        for (int c = 0; c < 8; c++) {
            int m = i * 8 + c;
            __syncthreads();   // drain stage(m); all reads of buf[(m+1)&1] done
            pk += 262144;                   // chunk + 1
            if (c == 7) pk += 2097152;      // head boundary: total +4MB per i
            if (m < 63) {
                char* lb = (char*)Kc[(c + 1) & 1] + ldsoff;
                #pragma unroll
                for (int j = 0; j < 4; j++)
                    async16(lb + j * 8192, pk + (long)j * 65536);
            }
            const char* kc = (const char*)Kc[c & 1];
            f32x4 sv = {0.f, 0.f, 0.f, 0.f};
            #pragma unroll
            for (int kk = 0; kk < 4; kk++) {
                f16x8 bk = *(const f16x8*)(kc + rdoff[kk]);
                sv = __builtin_amdgcn_mfma_f32_16x16x32_f16(aq[kk], bk, sv, 0, 0, 0);
            }
            #pragma unroll
            for (int r = 0; r < 4; r++) {
                float e = __expf(sv[r] * scale);
                s[c][r] = e;
                rs[r] += e;
            }
        }
        // row-sum reduce: across l15 lanes, then across all 8 waves
        #pragma unroll
        for (int off = 1; off < 16; off <<= 1)
            #pragma unroll
            for (int r = 0; r < 4; r++) rs[r] += __shfl_xor(rs[r], off, 64);
        if (l15 == 0) {
            #pragma unroll
            for (int r = 0; r < 4; r++) red[wave][lg * 4 + r] = rs[r];
        }
        __syncthreads();
        #pragma unroll
        for (int r = 0; r < 4; r++) {
            int row = lg * 4 + r;
            float tot = red[0][row] + red[1][row] + red[2][row] + red[3][row]
                      + red[4][row] + red[5][row] + red[6][row] + red[7][row];
            float rinv = 0.125f / tot;
            #pragma unroll
            for (int c = 0; c < 8; c++) acc[c][r] += s[c][r] * rinv;
        }
        __syncthreads();   // red reads done before next i's writes
    }

    long rbase = ((long)(bh * 1024 + t0)) * 1024;
    #pragma unroll
    for (int c = 0; c < 8; c++) {
        int scol = c * 128 + cw * 64 + sw * 16 + l15;
        #pragma unroll
        for (int r = 0; r < 4; r++) {
            long idx = rbase + (long)(lg * 4 + r) * 1024 + scol;
            attn_out[idx] = acc[c][r];
            Pbar[idx] = (_Float16)acc[c][r];
        }
    }
}

extern "C" void kernel_launch(void* const* d_in, const int* in_sizes, int n_in,
                              void* d_out, int out_size, void* d_ws, size_t ws_size,
                              hipStream_t stream) {
    const long M1 = 1048576;
    _Float16* ws = (_Float16*)d_ws;
    _Float16* q16  = ws;             // 2M elts (query; key at +2M, value at +4M)
    _Float16* wq16 = ws + 6 * M1;    // 8M (Wk at +8M, Wv at +16M -> contiguous for z-indexed B)
    _Float16* wo16 = ws + 23 * M1;   // 1M
    _Float16* Qbuf = ws + 24 * M1;   // 16M (Kbuf at +16M, Vbuf at +32M)
    _Float16* Vbuf = ws + 56 * M1;   // 2M  (== Qbuf + 32M)
    _Float16* Vt   = ws + 58 * M1;   // 2M
    _Float16* Pb   = ws + 60 * M1;   // 16M
    _Float16* Hbar = ws + 76 * M1;   // 2M
    float* out = (float*)d_out;
    float* attn_out = out + 2 * M1;

    // all 7 casts in one dispatch
    cast_all<<<2048, 256, 0, stream>>>(
        (const float*)d_in[0], (const float*)d_in[1], (const float*)d_in[2],
        (const float*)d_in[3], (const float*)d_in[4], (const float*)d_in[5],
        (const float*)d_in[6], ws);

    // Projections, one dispatch (XCD-chunk swizzled flat grid):
    // z=0..7 Q_i = query @ Wq[i]^T; z=8..15 K_i; z=16 V = value @ Wv^T.
    gemm_bt<4, 1><<<2176, 256, 0, stream>>>(
        q16, wq16, Qbuf, 1024, 1024, 1024, 1024,
        /*az*/ 8, 2 * M1, 0, /*sb*/ M1,
        /*cz*/ 16, 32 * M1, 2 * M1, /*f32*/ 0);
    // V transpose -> Vt[b][e][s]
    transpose_v<<<dim3(16, 16, 2), 256, 0, stream>>>(Vbuf, Vt);
    // fused scores+softmax+mean_i -> attention (f32) + Pbar (f16)
    attn_fused<<<1024, 512, 0, stream>>>(Qbuf, Qbuf + 16 * M1, attn_out, Pb);
    // PV: head[b][t][h*128+n] = sum_s Pbar[(b,h)][t][s] * Vt[b][h*128+n][s]
    gemm_bt<2, 0><<<dim3(1, 16, 16), 256, 0, stream>>>(
        Pb, Vt, Hbar, 1024, 1024, 1024, 1024,
        /*az*/ 16, 0, M1, /*sb*/ M1 / 8,
        /*cz*/ 8, M1, 128, /*f32*/ 0);
    // out = head_mean @ Wo^T  (f32 out)
    gemm_bt<2, 0><<<dim3(8, 32, 1), 256, 0, stream>>>(
        Hbar, wo16, out, 1024, 1024, 1024, 1024,
        1, 0, 0, 0, 1, 0, 0, /*f32*/ 1);
}